// Round 2
// baseline (319.958 us; speedup 1.0000x reference)
//
#include <hip/hip_runtime.h>
#include <math.h>

// Problem constants
#define B_    8
#define L_    384
#define Q_    64
#define H_    256
#define TP1   10
#define R_    512          // B*Q rows
#define P_    73920        // L*(L+1)/2 pairs
#define NF4   18480        // P_/4 float4s per row

// Workspace layout (float offsets). Total 1,444,864 floats = 5.78 MB.
#define WS_WVT   0          // 2*256*256 : WvT[c][hp][h] = Wv[h][c*256+hp]
#define WS_HIDT  131072     // 8*256*384 : hidT[b][h][v]
#define WS_QH    917504     // 512*512   : qh[r][j]
#define WS_G     1179648    // 512*512   : g[r][c*256+h]
#define WS_DOTC  1441792    // 512*2
#define WS_LOCS  1442816    // 512*2
#define WS_FACT  1443840    // 512*2

// ---------------------------------------------------------------- transpose
__global__ __launch_bounds__(256) void k_transpose(const float* __restrict__ hid,
                                                   const float* __restrict__ Wv,
                                                   float* __restrict__ ws) {
    int idx = blockIdx.x * 256 + threadIdx.x;   // grid = 3584 blocks exactly
    if (idx < 131072) {
        int c = idx >> 16, rem = idx & 65535;
        int hp = rem >> 8, h = rem & 255;
        ws[WS_WVT + idx] = Wv[h * 512 + c * 256 + hp];
    } else {
        int j = idx - 131072;                   // < 786432
        int b = j / 98304; int r2 = j - b * 98304;
        int h = r2 / 384;  int v = r2 - h * 384;
        ws[WS_HIDT + j] = hid[b * 98304 + v * 256 + h];
    }
}

// ---------------------------------------------------------------- QH = queries @ Wq + bq
__global__ __launch_bounds__(512) void k_qh(const float* __restrict__ queries,
                                            const float* __restrict__ Wq,
                                            const float* __restrict__ bq,
                                            float* ws) {
    __shared__ float q[8][256];
    int tid = threadIdx.x;
    int row0 = blockIdx.x * 8;                  // grid = 64
    for (int i = tid; i < 2048; i += 512)
        q[i >> 8][i & 255] = queries[row0 * 256 + i];
    __syncthreads();
    float acc[8] = {0, 0, 0, 0, 0, 0, 0, 0};
    int j = tid;
    for (int h = 0; h < 256; h += 4) {
        float w0 = Wq[(h + 0) * 512 + j];
        float w1 = Wq[(h + 1) * 512 + j];
        float w2 = Wq[(h + 2) * 512 + j];
        float w3 = Wq[(h + 3) * 512 + j];
#pragma unroll
        for (int r = 0; r < 8; r++) {
            float4 qv = *reinterpret_cast<const float4*>(&q[r][h]);
            acc[r] += qv.x * w0 + qv.y * w1 + qv.z * w2 + qv.w * w3;
        }
    }
    float bj = bq[j];
#pragma unroll
    for (int r = 0; r < 8; r++)
        ws[WS_QH + (row0 + r) * 512 + j] = acc[r] + bj;
}

// ---------------------------------------------------------------- per-row small stuff
__global__ __launch_bounds__(64) void k_rowsmall(const float* __restrict__ queries,
                                                 const float* __restrict__ qlocs,
                                                 const float* __restrict__ qlogits,
                                                 const float* __restrict__ Wc,
                                                 const float* __restrict__ bc,
                                                 const float* __restrict__ bv,
                                                 const float* __restrict__ Wo,
                                                 const float* __restrict__ bo,
                                                 const float* __restrict__ Wf,
                                                 const float* __restrict__ bf,
                                                 float* ws, float* out) {
    int r = blockIdx.x;                          // grid = 512
    int lane = threadIdx.x;
    float q0 = queries[r * 256 + lane];
    float q1 = queries[r * 256 + lane + 64];
    float q2 = queries[r * 256 + lane + 128];
    float q3 = queries[r * 256 + lane + 192];

    // labels: softmax(logits + q@Wc + bc)
    float x[10];
#pragma unroll
    for (int t = 0; t < 10; t++) {
        float v = q0 * Wc[lane * 10 + t] + q1 * Wc[(lane + 64) * 10 + t]
                + q2 * Wc[(lane + 128) * 10 + t] + q3 * Wc[(lane + 192) * 10 + t];
#pragma unroll
        for (int off = 32; off; off >>= 1) v += __shfl_xor(v, off);
        x[t] = qlogits[r * 10 + t] + bc[t] + v;
    }
    float m = -1e30f;
#pragma unroll
    for (int t = 0; t < 10; t++) m = fmaxf(m, x[t]);
    float s = 0.f;
#pragma unroll
    for (int t = 0; t < 10; t++) { x[t] = expf(x[t] - m); s += x[t]; }
    float inv = 1.0f / s;
    if (lane == 0) {
#pragma unroll
        for (int t = 0; t < 10; t++) out[r * 10 + t] = x[t] * inv;
    }

    // offset -> locs, factors = softplus(q@Wf + bf)
#pragma unroll
    for (int k = 0; k < 2; k++) {
        float vo = q0 * Wo[lane * 2 + k] + q1 * Wo[(lane + 64) * 2 + k]
                 + q2 * Wo[(lane + 128) * 2 + k] + q3 * Wo[(lane + 192) * 2 + k];
        float vf = q0 * Wf[lane * 2 + k] + q1 * Wf[(lane + 64) * 2 + k]
                 + q2 * Wf[(lane + 128) * 2 + k] + q3 * Wf[(lane + 192) * 2 + k];
#pragma unroll
        for (int off = 32; off; off >>= 1) { vo += __shfl_xor(vo, off); vf += __shfl_xor(vf, off); }
        if (lane == 0) {
            ws[WS_LOCS + r * 2 + k] = qlocs[r * 2 + k] + vo + bo[k];
            float xx = vf + bf[k];
            ws[WS_FACT + r * 2 + k] = (xx > 20.f) ? xx : log1pf(expf(xx));
        }
    }

    // dotc[c] = qh[r,c,:] . bv[c,:]
#pragma unroll
    for (int c = 0; c < 2; c++) {
        float v = 0.f;
#pragma unroll
        for (int i = 0; i < 4; i++) {
            int h = lane + 64 * i;
            v += ws[WS_QH + r * 512 + c * 256 + h] * bv[c * 256 + h];
        }
#pragma unroll
        for (int off = 32; off; off >>= 1) v += __shfl_xor(v, off);
        if (lane == 0) ws[WS_DOTC + r * 2 + c] = v;
    }
}

// ---------------------------------------------------------------- g[r,c,h] = sum_hp qh[r,c,hp] * WvT[c][hp][h]
__global__ __launch_bounds__(512) void k_g(float* ws) {
    __shared__ float qh[8][512];
    int tid = threadIdx.x;
    int row0 = blockIdx.x * 8;                  // grid = 64
    for (int i = tid; i < 4096; i += 512)
        qh[i >> 9][i & 511] = ws[WS_QH + row0 * 512 + i];
    __syncthreads();
    int c = tid >> 8, h = tid & 255;
    const float* wvt = ws + WS_WVT + c * 65536 + h;
    float acc[8] = {0, 0, 0, 0, 0, 0, 0, 0};
    for (int hp = 0; hp < 256; hp += 4) {
        float w0 = wvt[(hp + 0) * 256];
        float w1 = wvt[(hp + 1) * 256];
        float w2 = wvt[(hp + 2) * 256];
        float w3 = wvt[(hp + 3) * 256];
#pragma unroll
        for (int r = 0; r < 8; r++) {
            float4 qv = *reinterpret_cast<const float4*>(&qh[r][c * 256 + hp]);
            acc[r] += qv.x * w0 + qv.y * w1 + qv.z * w2 + qv.w * w3;
        }
    }
#pragma unroll
    for (int r = 0; r < 8; r++)
        ws[WS_G + (row0 + r) * 512 + tid] = acc[r];
}

// ---------------------------------------------------------------- helpers
__device__ __forceinline__ float blockReduceMax(float v, float* red, int tid) {
    red[tid] = v; __syncthreads();
    for (int s = 128; s > 0; s >>= 1) {
        if (tid < s) red[tid] = fmaxf(red[tid], red[tid + s]);
        __syncthreads();
    }
    float r = red[0]; __syncthreads();
    return r;
}
__device__ __forceinline__ float blockReduceSum(float v, float* red, int tid) {
    red[tid] = v; __syncthreads();
    for (int s = 128; s > 0; s >>= 1) {
        if (tid < s) red[tid] += red[tid + s];
        __syncthreads();
    }
    float r = red[0]; __syncthreads();
    return r;
}

// ---------------------------------------------------------------- main: score -> factorized pair softmax -> write
__global__ __launch_bounds__(256) void k_main(const float* ws,
                                              const int* __restrict__ mask,
                                              float* __restrict__ out) {
    __shared__ float g0[256], g1[256];
    __shared__ float s0[384], s1[384];
    __shared__ float Ex[384], Ey[384];
    __shared__ float ps[512];
    __shared__ float red[256];

    int tid = threadIdx.x;
    int r = blockIdx.x;                         // grid = 512
    int b = r >> 6;

    g0[tid] = ws[WS_G + r * 512 + tid];
    g1[tid] = ws[WS_G + r * 512 + 256 + tid];
    float dotc0 = ws[WS_DOTC + r * 2 + 0];
    float dotc1 = ws[WS_DOTC + r * 2 + 1];
    float lx = ws[WS_LOCS + r * 2 + 0], ly = ws[WS_LOCS + r * 2 + 1];
    float fx = ws[WS_FACT + r * 2 + 0], fy = ws[WS_FACT + r * 2 + 1];
    __syncthreads();

    const float* hT = ws + WS_HIDT + b * 98304;
    // score for v = tid (0..255)
    {
        int v = tid;
        float a0 = 0.f, a1 = 0.f;
        const float* p = hT + v;
#pragma unroll 4
        for (int h = 0; h < 256; h++) {
            float x = p[h * 384];
            a0 += x * g0[h];
            a1 += x * g1[h];
        }
        bool mk = mask[b * 384 + v] != 0;
        s0[v] = mk ? (a0 + dotc0) * 0.0625f : -1e8f;
        s1[v] = mk ? (a1 + dotc1) * 0.0625f : -1e8f;
    }
    if (tid < 128) {                            // v = 256..383
        int v = 256 + tid;
        float a0 = 0.f, a1 = 0.f;
        const float* p = hT + v;
#pragma unroll 4
        for (int h = 0; h < 256; h++) {
            float x = p[h * 384];
            a0 += x * g0[h];
            a1 += x * g1[h];
        }
        bool mk = mask[b * 384 + v] != 0;
        s0[v] = mk ? (a0 + dotc0) * 0.0625f : -1e8f;
        s1[v] = mk ? (a1 + dotc1) * 0.0625f : -1e8f;
    }
    __syncthreads();

    // inclusive prefix-max of s0 (Hillis-Steele over 512, identity -1e30)
    ps[tid] = s0[tid];
    ps[tid + 256] = (tid < 128) ? s0[tid + 256] : -1e30f;
    __syncthreads();
    for (int off = 1; off < 512; off <<= 1) {
        float a0 = (tid >= off) ? ps[tid - off] : -1e30f;
        float a1 = ps[tid + 256 - off];
        __syncthreads();
        ps[tid] = fmaxf(ps[tid], a0);
        ps[tid + 256] = fmaxf(ps[tid + 256], a1);
        __syncthreads();
    }
    float m0 = ps[383];
    // m = max_e (s1[e] + prefmax0[e]);  m1 = max_e s1[e]
    float lm, lm1;
    { int e = tid; lm = s1[e] + ps[e]; lm1 = s1[e]; }
    if (tid < 128) { int e = tid + 256; lm = fmaxf(lm, s1[e] + ps[e]); lm1 = fmaxf(lm1, s1[e]); }
    float mM = blockReduceMax(lm, red, tid);
    float m1 = blockReduceMax(lm1, red, tid);

    // Ex, Ey
    {
        int i = tid;
        float ds = (float)i - lx;
        Ex[i] = expf(s0[i] - m0 - fx * ds * ds);
        float de = (float)i - ly;
        float mk = (mask[b * 384 + i] != 0) ? 1.f : 0.f;
        Ey[i] = mk * expf(s1[i] - m1 - fy * de * de);
    }
    if (tid < 128) {
        int i = tid + 256;
        float ds = (float)i - lx;
        Ex[i] = expf(s0[i] - m0 - fx * ds * ds);
        float de = (float)i - ly;
        float mk = (mask[b * 384 + i] != 0) ? 1.f : 0.f;
        Ey[i] = mk * expf(s1[i] - m1 - fy * de * de);
    }
    __syncthreads();

    // inclusive prefix-sum of Ex
    ps[tid] = Ex[tid];
    ps[tid + 256] = (tid < 128) ? Ex[tid + 256] : 0.f;
    __syncthreads();
    for (int off = 1; off < 512; off <<= 1) {
        float a0 = (tid >= off) ? ps[tid - off] : 0.f;
        float a1 = ps[tid + 256 - off];
        __syncthreads();
        ps[tid] += a0;
        ps[tid + 256] += a1;
        __syncthreads();
    }
    // S2 = sum_e Ey[e] * prefsum(Ex)[e]
    float lsum = Ey[tid] * ps[tid];
    if (tid < 128) lsum += Ey[tid + 256] * ps[tid + 256];
    float S2 = blockReduceSum(lsum, red, tid);

    float C = expf(m0 + m1 - mM);
    float scale = C / (C * S2 + 1e-12f);
    // fold scale into Ey (all reads of Ey for S2 done before this point)
    Ey[tid] *= scale;
    if (tid < 128) Ey[tid + 256] *= scale;
    __syncthreads();

    // write phase: out[p] = Ex[s] * Ey_scaled[e], p = e(e+1)/2 + s, float4 streamed
    float* ob = out + 5120 + r * 73920;
    for (int idx = tid; idx < NF4; idx += 256) {
        int p0 = idx << 2;
        int e = (int)((sqrtf(8.f * (float)p0 + 1.f) - 1.f) * 0.5f);
        int tri = (e * (e + 1)) >> 1;
        while (tri > p0) { e--; tri -= (e + 1); }
        while (p0 - tri > e) { tri += (e + 1); e++; }
        int s = p0 - tri;
        float ey = Ey[e];
        float4 v;
        v.x = Ex[s] * ey; if (++s > e) { s = 0; ey = Ey[++e]; }
        v.y = Ex[s] * ey; if (++s > e) { s = 0; ey = Ey[++e]; }
        v.z = Ex[s] * ey; if (++s > e) { s = 0; ey = Ey[++e]; }
        v.w = Ex[s] * ey;
        reinterpret_cast<float4*>(ob)[idx] = v;
    }
}

// ---------------------------------------------------------------- launch
extern "C" void kernel_launch(void* const* d_in, const int* in_sizes, int n_in,
                              void* d_out, int out_size, void* d_ws, size_t ws_size,
                              hipStream_t stream) {
    const float* hiddens = (const float*)d_in[0];
    const int* masks     = (const int*)d_in[1];   // jax bool -> int32 in harness
    const float* queries = (const float*)d_in[2];
    const float* qlocs   = (const float*)d_in[3];
    const float* qlogits = (const float*)d_in[4];
    const float* Wc = (const float*)d_in[5];
    const float* bc = (const float*)d_in[6];
    const float* Wq = (const float*)d_in[7];
    const float* bq = (const float*)d_in[8];
    const float* Wv = (const float*)d_in[9];
    const float* bv = (const float*)d_in[10];
    const float* Wo = (const float*)d_in[11];
    const float* bo = (const float*)d_in[12];
    const float* Wf = (const float*)d_in[13];
    const float* bf = (const float*)d_in[14];
    float* out = (float*)d_out;
    float* ws  = (float*)d_ws;     // needs 5.78 MB

    hipLaunchKernelGGL(k_transpose, dim3(3584), dim3(256), 0, stream, hiddens, Wv, ws);
    hipLaunchKernelGGL(k_qh,        dim3(64),   dim3(512), 0, stream, queries, Wq, bq, ws);
    hipLaunchKernelGGL(k_rowsmall,  dim3(512),  dim3(64),  0, stream, queries, qlocs, qlogits,
                       Wc, bc, bv, Wo, bo, Wf, bf, ws, out);
    hipLaunchKernelGGL(k_g,         dim3(64),   dim3(512), 0, stream, ws);
    hipLaunchKernelGGL(k_main,      dim3(512),  dim3(256), 0, stream, ws, masks, out);
}

// Round 3
// 294.198 us; speedup vs baseline: 1.0876x; 1.0876x over previous
//
#include <hip/hip_runtime.h>
#include <math.h>

// Problem constants
#define B_    8
#define L_    384
#define Q_    64
#define H_    256
#define R_    512          // B*Q rows
#define P_    73920        // L*(L+1)/2 pairs
#define NF4   18480        // P_/4 float4s per row
#define QF4   4620         // NF4/4 float4s per quarter-row block

// Workspace layout (float offsets). Total 1,837,056 floats = 7.35 MB.
#define WS_WVT   0          // 512*256   : WvT[j][h] = Wv[h][j]   (j = c*256+hp)
#define WS_HIDT  131072     // 8*256*384 : hidT[b][h][v]
#define WS_QH    917504     // 512*512   : qh[r][j]
#define WS_G     1179648    // 512*512   : g[r][c*256+h]
#define WS_LOCS  1441792    // 512*2
#define WS_FACT  1442816    // 512*2
#define WS_EXEY  1443840    // 512*768   : per row: Ex[384], Ey_scaled[384]

// ---------------------------------------------------------------- tiled 64x64 transpose helper
// in: M x N row-major; out: N x M row-major. Block = 256 threads, one 64x64 tile.
__device__ __forceinline__ void tile_transpose(const float* __restrict__ in,
                                               float* __restrict__ outp,
                                               int M, int N, int mt, int nt,
                                               float* smem /* >= 64*65 floats */) {
    float (*t)[65] = (float(*)[65])smem;
    int lane = threadIdx.x & 63, row4 = threadIdx.x >> 6;   // 0..3
    int m0 = mt * 64, n0 = nt * 64;
#pragma unroll
    for (int p = 0; p < 16; p++) {
        int m = m0 + p * 4 + row4;
        t[p * 4 + row4][lane] = in[m * N + n0 + lane];
    }
    __syncthreads();
#pragma unroll
    for (int p = 0; p < 16; p++) {
        int n = n0 + p * 4 + row4;
        outp[n * M + m0 + lane] = t[lane][p * 4 + row4];
    }
}

// ---------------------------------------------------------------- F1: transposes + qh GEMM + per-row small stuff
// grid = 480 blocks x 256 threads:
//   [0,192)   : hidT tiles (8 b x 24 tiles)
//   [192,224) : WvT tiles (32 tiles)
//   [224,352) : qh (128 blocks, 4 rows each)
//   [352,480) : rowsmall (128 blocks, 4 rows each, wave per row)
__global__ __launch_bounds__(256) void k_f1(const float* __restrict__ hid,
                                            const float* __restrict__ Wv,
                                            const float* __restrict__ queries,
                                            const float* __restrict__ Wq,
                                            const float* __restrict__ bq_p,
                                            const float* __restrict__ qlocs,
                                            const float* __restrict__ qlogits,
                                            const float* __restrict__ Wc,
                                            const float* __restrict__ bc,
                                            const float* __restrict__ Wo,
                                            const float* __restrict__ bo,
                                            const float* __restrict__ Wf,
                                            const float* __restrict__ bf,
                                            float* __restrict__ ws,
                                            float* __restrict__ out) {
    __shared__ float smem[64 * 65];
    int blk = blockIdx.x;
    int tid = threadIdx.x;

    if (blk < 192) {
        int b = blk / 24, t = blk % 24;
        int mt = t % 6, nt = t / 6;                 // M=384 (v), N=256 (h)
        tile_transpose(hid + b * 98304, ws + WS_HIDT + b * 98304, 384, 256, mt, nt, smem);
        return;
    }
    if (blk < 224) {
        int t = blk - 192;                          // M=256 (h), N=512 (j)
        int mt = t % 4, nt = t / 4;
        tile_transpose(Wv, ws + WS_WVT, 256, 512, mt, nt, smem);
        return;
    }
    if (blk < 352) {
        // qh[r][j] = queries[r] @ Wq[:,j] + bq[j], 4 rows per block, j in {tid, tid+256}
        int row0 = (blk - 224) * 4;
        float (*q)[256] = (float(*)[256])smem;
        for (int i = tid; i < 1024; i += 256)
            q[i >> 8][i & 255] = queries[row0 * 256 + i];
        __syncthreads();
        float acc0[4] = {0, 0, 0, 0}, acc1[4] = {0, 0, 0, 0};
        int j0 = tid, j1 = tid + 256;
        for (int h = 0; h < 256; h += 2) {
            float wa0 = Wq[h * 512 + j0],       wa1 = Wq[h * 512 + j1];
            float wb0 = Wq[(h + 1) * 512 + j0], wb1 = Wq[(h + 1) * 512 + j1];
#pragma unroll
            for (int r = 0; r < 4; r++) {
                float qa = q[r][h], qb = q[r][h + 1];
                acc0[r] += qa * wa0 + qb * wb0;
                acc1[r] += qa * wa1 + qb * wb1;
            }
        }
        float b0 = bq_p[j0], b1 = bq_p[j1];
#pragma unroll
        for (int r = 0; r < 4; r++) {
            ws[WS_QH + (row0 + r) * 512 + j0] = acc0[r] + b0;
            ws[WS_QH + (row0 + r) * 512 + j1] = acc1[r] + b1;
        }
        return;
    }
    {
        // rowsmall: wave per row
        int r = (blk - 352) * 4 + (tid >> 6);
        int lane = tid & 63;
        float q0 = queries[r * 256 + lane];
        float q1 = queries[r * 256 + lane + 64];
        float q2 = queries[r * 256 + lane + 128];
        float q3 = queries[r * 256 + lane + 192];

        float x[10];
#pragma unroll
        for (int t = 0; t < 10; t++) {
            float v = q0 * Wc[lane * 10 + t] + q1 * Wc[(lane + 64) * 10 + t]
                    + q2 * Wc[(lane + 128) * 10 + t] + q3 * Wc[(lane + 192) * 10 + t];
#pragma unroll
            for (int off = 32; off; off >>= 1) v += __shfl_xor(v, off);
            x[t] = qlogits[r * 10 + t] + bc[t] + v;
        }
        float m = -1e30f;
#pragma unroll
        for (int t = 0; t < 10; t++) m = fmaxf(m, x[t]);
        float s = 0.f;
#pragma unroll
        for (int t = 0; t < 10; t++) { x[t] = expf(x[t] - m); s += x[t]; }
        float inv = 1.0f / s;
        if (lane == 0) {
#pragma unroll
            for (int t = 0; t < 10; t++) out[r * 10 + t] = x[t] * inv;
        }

#pragma unroll
        for (int k = 0; k < 2; k++) {
            float vo = q0 * Wo[lane * 2 + k] + q1 * Wo[(lane + 64) * 2 + k]
                     + q2 * Wo[(lane + 128) * 2 + k] + q3 * Wo[(lane + 192) * 2 + k];
            float vf = q0 * Wf[lane * 2 + k] + q1 * Wf[(lane + 64) * 2 + k]
                     + q2 * Wf[(lane + 128) * 2 + k] + q3 * Wf[(lane + 192) * 2 + k];
#pragma unroll
            for (int off = 32; off; off >>= 1) { vo += __shfl_xor(vo, off); vf += __shfl_xor(vf, off); }
            if (lane == 0) {
                ws[WS_LOCS + r * 2 + k] = qlocs[r * 2 + k] + vo + bo[k];
                float xx = vf + bf[k];
                ws[WS_FACT + r * 2 + k] = (xx > 20.f) ? xx : log1pf(expf(xx));
            }
        }
    }
}

// ---------------------------------------------------------------- F2: g[r,c,h] = sum_hp qh[r,c,hp] * WvT[c*256+hp][h]
__global__ __launch_bounds__(512) void k_g(float* ws) {
    __shared__ float qh[8][512];
    int tid = threadIdx.x;
    int row0 = blockIdx.x * 8;                  // grid = 64
    for (int i = tid; i < 4096; i += 512)
        qh[i >> 9][i & 511] = ws[WS_QH + row0 * 512 + i];
    __syncthreads();
    int c = tid >> 8, h = tid & 255;
    const float* wvt = ws + WS_WVT + c * 65536 + h;
    float acc[8] = {0, 0, 0, 0, 0, 0, 0, 0};
    for (int hp = 0; hp < 256; hp += 4) {
        float w0 = wvt[(hp + 0) * 256];
        float w1 = wvt[(hp + 1) * 256];
        float w2 = wvt[(hp + 2) * 256];
        float w3 = wvt[(hp + 3) * 256];
#pragma unroll
        for (int r = 0; r < 8; r++) {
            float4 qv = *reinterpret_cast<const float4*>(&qh[r][c * 256 + hp]);
            acc[r] += qv.x * w0 + qv.y * w1 + qv.z * w2 + qv.w * w3;
        }
    }
#pragma unroll
    for (int r = 0; r < 8; r++)
        ws[WS_G + (row0 + r) * 512 + tid] = acc[r];
}

// ---------------------------------------------------------------- reduce helpers (256 threads)
__device__ __forceinline__ float blockReduceMax(float v, float* red, int tid) {
    red[tid] = v; __syncthreads();
    for (int s = 128; s > 0; s >>= 1) {
        if (tid < s) red[tid] = fmaxf(red[tid], red[tid + s]);
        __syncthreads();
    }
    float r = red[0]; __syncthreads();
    return r;
}
__device__ __forceinline__ float blockReduceSum(float v, float* red, int tid) {
    red[tid] = v; __syncthreads();
    for (int s = 128; s > 0; s >>= 1) {
        if (tid < s) red[tid] += red[tid + s];
        __syncthreads();
    }
    float r = red[0]; __syncthreads();
    return r;
}

// ---------------------------------------------------------------- F3: per-row scores -> factorized softmax prep
__global__ __launch_bounds__(256) void k_prep(const float* __restrict__ ws_c,
                                              float* __restrict__ ws,
                                              const int* __restrict__ mask,
                                              const float* __restrict__ bv) {
    __shared__ float g0[256], g1[256];
    __shared__ float s0[384], s1[384];
    __shared__ float Ex[384], Ey[384];
    __shared__ float ps[512];
    __shared__ float red[256];

    int tid = threadIdx.x;
    int r = blockIdx.x;                         // grid = 512
    int b = r >> 6;

    g0[tid] = ws_c[WS_G + r * 512 + tid];
    g1[tid] = ws_c[WS_G + r * 512 + 256 + tid];
    float lx = ws_c[WS_LOCS + r * 2 + 0], ly = ws_c[WS_LOCS + r * 2 + 1];
    float fx = ws_c[WS_FACT + r * 2 + 0], fy = ws_c[WS_FACT + r * 2 + 1];

    // dotc inline from qh . bv
    float p0v = ws_c[WS_QH + r * 512 + tid] * bv[tid];
    float p1v = ws_c[WS_QH + r * 512 + 256 + tid] * bv[256 + tid];
    float dotc0 = blockReduceSum(p0v, red, tid);
    float dotc1 = blockReduceSum(p1v, red, tid);
    __syncthreads();

    const float* hT = ws_c + WS_HIDT + b * 98304;
    {
        int v = tid;
        float a0 = 0.f, a1 = 0.f;
        const float* p = hT + v;
#pragma unroll 8
        for (int h = 0; h < 256; h++) {
            float x = p[h * 384];
            a0 += x * g0[h];
            a1 += x * g1[h];
        }
        bool mk = mask[b * 384 + v] != 0;
        s0[v] = mk ? (a0 + dotc0) * 0.0625f : -1e8f;
        s1[v] = mk ? (a1 + dotc1) * 0.0625f : -1e8f;
    }
    if (tid < 128) {
        int v = 256 + tid;
        float a0 = 0.f, a1 = 0.f;
        const float* p = hT + v;
#pragma unroll 8
        for (int h = 0; h < 256; h++) {
            float x = p[h * 384];
            a0 += x * g0[h];
            a1 += x * g1[h];
        }
        bool mk = mask[b * 384 + v] != 0;
        s0[v] = mk ? (a0 + dotc0) * 0.0625f : -1e8f;
        s1[v] = mk ? (a1 + dotc1) * 0.0625f : -1e8f;
    }
    __syncthreads();

    // inclusive prefix-max of s0
    ps[tid] = s0[tid];
    ps[tid + 256] = (tid < 128) ? s0[tid + 256] : -1e30f;
    __syncthreads();
    for (int off = 1; off < 512; off <<= 1) {
        float a0 = (tid >= off) ? ps[tid - off] : -1e30f;
        float a1 = ps[tid + 256 - off];
        __syncthreads();
        ps[tid] = fmaxf(ps[tid], a0);
        ps[tid + 256] = fmaxf(ps[tid + 256], a1);
        __syncthreads();
    }
    float m0 = ps[383];
    float lm, lm1;
    { int e = tid; lm = s1[e] + ps[e]; lm1 = s1[e]; }
    if (tid < 128) { int e = tid + 256; lm = fmaxf(lm, s1[e] + ps[e]); lm1 = fmaxf(lm1, s1[e]); }
    float mM = blockReduceMax(lm, red, tid);
    float m1 = blockReduceMax(lm1, red, tid);

    {
        int i = tid;
        float ds = (float)i - lx;
        Ex[i] = expf(s0[i] - m0 - fx * ds * ds);
        float de = (float)i - ly;
        float mk = (mask[b * 384 + i] != 0) ? 1.f : 0.f;
        Ey[i] = mk * expf(s1[i] - m1 - fy * de * de);
    }
    if (tid < 128) {
        int i = tid + 256;
        float ds = (float)i - lx;
        Ex[i] = expf(s0[i] - m0 - fx * ds * ds);
        float de = (float)i - ly;
        float mk = (mask[b * 384 + i] != 0) ? 1.f : 0.f;
        Ey[i] = mk * expf(s1[i] - m1 - fy * de * de);
    }
    __syncthreads();

    // inclusive prefix-sum of Ex
    ps[tid] = Ex[tid];
    ps[tid + 256] = (tid < 128) ? Ex[tid + 256] : 0.f;
    __syncthreads();
    for (int off = 1; off < 512; off <<= 1) {
        float a0 = (tid >= off) ? ps[tid - off] : 0.f;
        float a1 = ps[tid + 256 - off];
        __syncthreads();
        ps[tid] += a0;
        ps[tid + 256] += a1;
        __syncthreads();
    }
    float lsum = Ey[tid] * ps[tid];
    if (tid < 128) lsum += Ey[tid + 256] * ps[tid + 256];
    float S2 = blockReduceSum(lsum, red, tid);

    float C = expf(m0 + m1 - mM);
    float scale = C / (C * S2 + 1e-12f);

    float* exr = ws + WS_EXEY + r * 768;
    exr[tid]       = Ex[tid];
    exr[384 + tid] = Ey[tid] * scale;
    if (tid < 128) {
        exr[256 + tid] = Ex[256 + tid];
        exr[640 + tid] = Ey[256 + tid] * scale;
    }
}

// ---------------------------------------------------------------- F4: stream writes  out[p] = Ex[s]*Ey[e]
__global__ __launch_bounds__(256) void k_write(const float* __restrict__ ws,
                                               float* __restrict__ out) {
    __shared__ float exey[768];
    int tid = threadIdx.x;
    int r = blockIdx.x >> 2, q = blockIdx.x & 3;   // grid = 2048
    const float* exr = ws + WS_EXEY + r * 768;
    for (int i = tid; i < 768; i += 256) exey[i] = exr[i];
    __syncthreads();
    const float* Ex = exey;
    const float* Ey = exey + 384;

    float* ob = out + 5120 + r * 73920;
    int base = q * QF4;
    int end = base + QF4;
    for (int idx = base + tid; idx < end; idx += 256) {
        int p0 = idx << 2;
        int e = (int)((sqrtf(8.f * (float)p0 + 1.f) - 1.f) * 0.5f);
        int tri = (e * (e + 1)) >> 1;
        while (tri > p0) { e--; tri -= (e + 1); }
        while (p0 - tri > e) { tri += (e + 1); e++; }
        int s = p0 - tri;
        float ey = Ey[e];
        float4 v;
        v.x = Ex[s] * ey; if (++s > e) { s = 0; ey = Ey[++e]; }
        v.y = Ex[s] * ey; if (++s > e) { s = 0; ey = Ey[++e]; }
        v.z = Ex[s] * ey; if (++s > e) { s = 0; ey = Ey[++e]; }
        v.w = Ex[s] * ey;
        reinterpret_cast<float4*>(ob)[idx] = v;
    }
}

// ---------------------------------------------------------------- launch
extern "C" void kernel_launch(void* const* d_in, const int* in_sizes, int n_in,
                              void* d_out, int out_size, void* d_ws, size_t ws_size,
                              hipStream_t stream) {
    const float* hiddens = (const float*)d_in[0];
    const int* masks     = (const int*)d_in[1];   // jax bool -> int32 in harness
    const float* queries = (const float*)d_in[2];
    const float* qlocs   = (const float*)d_in[3];
    const float* qlogits = (const float*)d_in[4];
    const float* Wc = (const float*)d_in[5];
    const float* bc = (const float*)d_in[6];
    const float* Wq = (const float*)d_in[7];
    const float* bq = (const float*)d_in[8];
    const float* Wv = (const float*)d_in[9];
    const float* bv = (const float*)d_in[10];
    const float* Wo = (const float*)d_in[11];
    const float* bo = (const float*)d_in[12];
    const float* Wf = (const float*)d_in[13];
    const float* bf = (const float*)d_in[14];
    float* out = (float*)d_out;
    float* ws  = (float*)d_ws;     // needs 7.35 MB

    hipLaunchKernelGGL(k_f1,    dim3(480),  dim3(256), 0, stream,
                       hiddens, Wv, queries, Wq, bq, qlocs, qlogits,
                       Wc, bc, Wo, bo, Wf, bf, ws, out);
    hipLaunchKernelGGL(k_g,     dim3(64),   dim3(512), 0, stream, ws);
    hipLaunchKernelGGL(k_prep,  dim3(512),  dim3(256), 0, stream, ws, ws, masks, bv);
    hipLaunchKernelGGL(k_write, dim3(2048), dim3(256), 0, stream, ws, out);
}

// Round 4
// 242.073 us; speedup vs baseline: 1.3217x; 1.2153x over previous
//
#include <hip/hip_runtime.h>
#include <math.h>

// Problem constants
#define B_    8
#define L_    384
#define Q_    64
#define H_    256
#define R_    512          // B*Q rows
#define P_    73920        // L*(L+1)/2 pairs
#define NF4   18480        // P_/4 float4s per row
#define QF4   4620         // NF4/4 float4s per quarter-row block

// Workspace layout (float offsets). Total 1,575,936 floats = 6.30 MB.
#define WS_WVT   0          // 512*256   : WvT[j][h] = Wv[h][j]   (j = c*256+hp)
#define WS_HIDT  131072     // 8*256*384 : hidT[b][h][v]
#define WS_G     917504     // 512*512   : g[r][c*256+h]
#define WS_DOTC  1179648    // 512*2
#define WS_LOCS  1180672    // 512*2
#define WS_FACT  1181696    // 512*2
#define WS_EXEY  1182720    // 512*768   : per row: Ex[384], Ey_scaled[384]

// ---------------------------------------------------------------- tiled 64x64 transpose helper
__device__ __forceinline__ void tile_transpose(const float* __restrict__ in,
                                               float* __restrict__ outp,
                                               int M, int N, int mt, int nt,
                                               float* smem /* >= 64*65 floats */) {
    float (*t)[65] = (float(*)[65])smem;
    int lane = threadIdx.x & 63, row4 = threadIdx.x >> 6;   // 0..3
    int m0 = mt * 64, n0 = nt * 64;
#pragma unroll
    for (int p = 0; p < 16; p++) {
        int m = m0 + p * 4 + row4;
        t[p * 4 + row4][lane] = in[m * N + n0 + lane];
    }
    __syncthreads();
#pragma unroll
    for (int p = 0; p < 16; p++) {
        int n = n0 + p * 4 + row4;
        outp[n * M + m0 + lane] = t[lane][p * 4 + row4];
    }
}

// ---------------------------------------------------------------- F1: transposes only
// grid = 224: [0,192) hidT (8 b x 24 tiles), [192,224) WvT (32 tiles)
__global__ __launch_bounds__(256) void k_front(const float* __restrict__ hid,
                                               const float* __restrict__ Wv,
                                               float* __restrict__ ws) {
    __shared__ float smem[64 * 65];
    int blk = blockIdx.x;
    if (blk < 192) {
        int b = blk / 24, t = blk % 24;
        int mt = t % 6, nt = t / 6;                 // M=384 (v), N=256 (h)
        tile_transpose(hid + b * 98304, ws + WS_HIDT + b * 98304, 384, 256, mt, nt, smem);
    } else {
        int t = blk - 192;                          // M=256 (h), N=512 (j)
        int mt = t % 4, nt = t / 4;
        tile_transpose(Wv, ws + WS_WVT, 256, 512, mt, nt, smem);
    }
}

// ---------------------------------------------------------------- F2: qh (LDS) -> g, dotc, rowsmall. 4 rows/block.
__global__ __launch_bounds__(512) void k_qhg(const float* __restrict__ queries,
                                             const float* __restrict__ Wq,
                                             const float* __restrict__ bq_p,
                                             const float* __restrict__ bv,
                                             const float* __restrict__ qlocs,
                                             const float* __restrict__ qlogits,
                                             const float* __restrict__ Wc,
                                             const float* __restrict__ bc,
                                             const float* __restrict__ Wo,
                                             const float* __restrict__ bo,
                                             const float* __restrict__ Wf,
                                             const float* __restrict__ bf,
                                             float* __restrict__ ws,
                                             float* __restrict__ out) {
    __shared__ float q[4][256];
    __shared__ float qh[4][512];
    int tid = threadIdx.x;
    int r0 = blockIdx.x * 4;                        // grid = 128

    for (int i = tid; i < 1024; i += 512)
        q[i >> 8][i & 255] = queries[r0 * 256 + i];
    __syncthreads();

    // Phase A: qh[r][j] = q[r]@Wq[:,j] + bq[j]
    {
        int j = tid;
        float acc[4] = {0, 0, 0, 0};
        for (int h = 0; h < 256; h += 2) {
            float wa = Wq[h * 512 + j];
            float wb = Wq[(h + 1) * 512 + j];
#pragma unroll
            for (int r = 0; r < 4; r++)
                acc[r] += q[r][h] * wa + q[r][h + 1] * wb;
        }
        float bj = bq_p[j];
#pragma unroll
        for (int r = 0; r < 4; r++) qh[r][j] = acc[r] + bj;
    }
    __syncthreads();

    // Phase B: g[r][c*256+h] = sum_hp qh[r][c*256+hp] * WvT[c*256+hp][h]
    {
        int c = tid >> 8, h = tid & 255;
        const float* wvt = ws + WS_WVT + c * 65536 + h;
        float acc[4] = {0, 0, 0, 0};
        for (int hp = 0; hp < 256; hp += 2) {
            float w0 = wvt[hp * 256];
            float w1 = wvt[(hp + 1) * 256];
#pragma unroll
            for (int r = 0; r < 4; r++)
                acc[r] += qh[r][c * 256 + hp] * w0 + qh[r][c * 256 + hp + 1] * w1;
        }
#pragma unroll
        for (int r = 0; r < 4; r++)
            ws[WS_G + (r0 + r) * 512 + tid] = acc[r];
    }

    // Phase C: dotc[r][c] = qh[r][c*256+:] . bv[c*256+:]  (wave w -> r=w>>1, c=w&1)
    {
        int w = tid >> 6, lane = tid & 63;
        int r = w >> 1, c = w & 1;
        float v = 0.f;
#pragma unroll
        for (int k = 0; k < 4; k++) {
            int h = lane + 64 * k;
            v += qh[r][c * 256 + h] * bv[c * 256 + h];
        }
#pragma unroll
        for (int off = 32; off; off >>= 1) v += __shfl_xor(v, off);
        if (lane == 0) ws[WS_DOTC + (r0 + r) * 2 + c] = v;
    }

    // Phase D: rowsmall, waves 0..3 -> row r0+w
    {
        int w = tid >> 6, lane = tid & 63;
        if (w < 4) {
            int r = r0 + w;
            float q0 = q[w][lane];
            float q1 = q[w][lane + 64];
            float q2 = q[w][lane + 128];
            float q3 = q[w][lane + 192];

            float x[10];
#pragma unroll
            for (int t = 0; t < 10; t++) {
                float v = q0 * Wc[lane * 10 + t] + q1 * Wc[(lane + 64) * 10 + t]
                        + q2 * Wc[(lane + 128) * 10 + t] + q3 * Wc[(lane + 192) * 10 + t];
#pragma unroll
                for (int off = 32; off; off >>= 1) v += __shfl_xor(v, off);
                x[t] = qlogits[r * 10 + t] + bc[t] + v;
            }
            float m = -1e30f;
#pragma unroll
            for (int t = 0; t < 10; t++) m = fmaxf(m, x[t]);
            float s = 0.f;
#pragma unroll
            for (int t = 0; t < 10; t++) { x[t] = expf(x[t] - m); s += x[t]; }
            float inv = 1.0f / s;
            if (lane == 0) {
#pragma unroll
                for (int t = 0; t < 10; t++) out[r * 10 + t] = x[t] * inv;
            }

#pragma unroll
            for (int k = 0; k < 2; k++) {
                float vo = q0 * Wo[lane * 2 + k] + q1 * Wo[(lane + 64) * 2 + k]
                         + q2 * Wo[(lane + 128) * 2 + k] + q3 * Wo[(lane + 192) * 2 + k];
                float vf = q0 * Wf[lane * 2 + k] + q1 * Wf[(lane + 64) * 2 + k]
                         + q2 * Wf[(lane + 128) * 2 + k] + q3 * Wf[(lane + 192) * 2 + k];
#pragma unroll
                for (int off = 32; off; off >>= 1) { vo += __shfl_xor(vo, off); vf += __shfl_xor(vf, off); }
                if (lane == 0) {
                    ws[WS_LOCS + r * 2 + k] = qlocs[r * 2 + k] + vo + bo[k];
                    float xx = vf + bf[k];
                    ws[WS_FACT + r * 2 + k] = (xx > 20.f) ? xx : log1pf(expf(xx));
                }
            }
        }
    }
}

// ---------------------------------------------------------------- F3: scores -> wave-scan factorized softmax prep
// block = 384 threads (6 waves), grid = 512 (one row each)
__global__ __launch_bounds__(384) void k_prep(const float* __restrict__ ws_c,
                                              float* __restrict__ ws,
                                              const int* __restrict__ mask) {
    __shared__ float g0[256], g1[256];
    __shared__ float s0[384], s1[384];
    __shared__ float Ex[384], Ey[384];
    __shared__ float scal[4];

    int tid = threadIdx.x;
    int r = blockIdx.x;                         // grid = 512
    int b = r >> 6;

    if (tid < 256) {
        g0[tid] = ws_c[WS_G + r * 512 + tid];
        g1[tid] = ws_c[WS_G + r * 512 + 256 + tid];
    }
    float dotc0 = ws_c[WS_DOTC + r * 2 + 0];
    float dotc1 = ws_c[WS_DOTC + r * 2 + 1];
    float lx = ws_c[WS_LOCS + r * 2 + 0], ly = ws_c[WS_LOCS + r * 2 + 1];
    float fx = ws_c[WS_FACT + r * 2 + 0], fy = ws_c[WS_FACT + r * 2 + 1];
    __syncthreads();

    // scores for v = tid (0..383)
    const float* hT = ws_c + WS_HIDT + b * 98304;
    float s0r, s1r;
    bool mk;
    {
        int v = tid;
        float a0 = 0.f, a1 = 0.f;
        const float* p = hT + v;
#pragma unroll 8
        for (int h = 0; h < 256; h++) {
            float x = p[h * 384];
            a0 += x * g0[h];
            a1 += x * g1[h];
        }
        mk = mask[b * 384 + v] != 0;
        s0r = mk ? (a0 + dotc0) * 0.0625f : -1e8f;
        s1r = mk ? (a1 + dotc1) * 0.0625f : -1e8f;
        s0[v] = s0r;
        s1[v] = s1r;
    }
    __syncthreads();

    // wave 0: prefix-max of s0, then mM = max_e(s1+pm), m1 = max s1, m0 = max s0
    if (tid < 64) {
        int l = tid;
        float p[6];
        p[0] = s0[l * 6 + 0];
#pragma unroll
        for (int k = 1; k < 6; k++) p[k] = fmaxf(p[k - 1], s0[l * 6 + k]);
        float run = p[5];
#pragma unroll
        for (int off = 1; off < 64; off <<= 1) {
            float t = __shfl_up(run, off);
            if (l >= off) run = fmaxf(run, t);
        }
        float excl = __shfl_up(run, 1);
        if (l == 0) excl = -1e30f;
        float m0 = __shfl(run, 63);
        float lm = -1e30f, lm1 = -1e30f;
#pragma unroll
        for (int k = 0; k < 6; k++) {
            float pm = fmaxf(excl, p[k]);
            float sv = s1[l * 6 + k];
            lm = fmaxf(lm, sv + pm);
            lm1 = fmaxf(lm1, sv);
        }
#pragma unroll
        for (int off = 1; off < 64; off <<= 1) {
            lm  = fmaxf(lm,  __shfl_xor(lm,  off));
            lm1 = fmaxf(lm1, __shfl_xor(lm1, off));
        }
        if (l == 0) { scal[0] = m0; scal[1] = lm1; scal[2] = lm; }
    }
    __syncthreads();

    // Ex, Ey (elementwise, i = tid)
    float m0 = scal[0], m1 = scal[1], mM = scal[2];
    float exv, eyv;
    {
        int i = tid;
        float ds = (float)i - lx;
        exv = expf(s0r - m0 - fx * ds * ds);
        float de = (float)i - ly;
        eyv = mk ? expf(s1r - m1 - fy * de * de) : 0.f;
        Ex[i] = exv;
        Ey[i] = eyv;
    }
    __syncthreads();

    // wave 0: prefix-sum of Ex, S2 = sum_e Ey[e]*psum[e], scale
    if (tid < 64) {
        int l = tid;
        float p[6];
        p[0] = Ex[l * 6 + 0];
#pragma unroll
        for (int k = 1; k < 6; k++) p[k] = p[k - 1] + Ex[l * 6 + k];
        float run = p[5];
#pragma unroll
        for (int off = 1; off < 64; off <<= 1) {
            float t = __shfl_up(run, off);
            if (l >= off) run += t;
        }
        float excl = __shfl_up(run, 1);
        if (l == 0) excl = 0.f;
        float s2l = 0.f;
#pragma unroll
        for (int k = 0; k < 6; k++)
            s2l += Ey[l * 6 + k] * (excl + p[k]);
#pragma unroll
        for (int off = 1; off < 64; off <<= 1) s2l += __shfl_xor(s2l, off);
        if (l == 0) {
            float C = expf(m0 + m1 - mM);
            scal[3] = C / (C * s2l + 1e-12f);
        }
    }
    __syncthreads();

    float scale = scal[3];
    float* exr = ws + WS_EXEY + r * 768;
    exr[tid]       = exv;
    exr[384 + tid] = eyv * scale;
}

// ---------------------------------------------------------------- F4: stream writes  out[p] = Ex[s]*Ey[e]
__global__ __launch_bounds__(256) void k_write(const float* __restrict__ ws,
                                               float* __restrict__ out) {
    __shared__ float exey[768];
    int tid = threadIdx.x;
    int r = blockIdx.x >> 2, q = blockIdx.x & 3;   // grid = 2048
    const float* exr = ws + WS_EXEY + r * 768;
    for (int i = tid; i < 768; i += 256) exey[i] = exr[i];
    __syncthreads();
    const float* Ex = exey;
    const float* Ey = exey + 384;

    float* ob = out + 5120 + r * 73920;
    int base = q * QF4;
    int end = base + QF4;
    for (int idx = base + tid; idx < end; idx += 256) {
        int p0 = idx << 2;
        int e = (int)((sqrtf(8.f * (float)p0 + 1.f) - 1.f) * 0.5f);
        int tri = (e * (e + 1)) >> 1;
        while (tri > p0) { e--; tri -= (e + 1); }
        while (p0 - tri > e) { tri += (e + 1); e++; }
        int s = p0 - tri;
        float ey = Ey[e];
        float4 v;
        v.x = Ex[s] * ey; if (++s > e) { s = 0; ey = Ey[++e]; }
        v.y = Ex[s] * ey; if (++s > e) { s = 0; ey = Ey[++e]; }
        v.z = Ex[s] * ey; if (++s > e) { s = 0; ey = Ey[++e]; }
        v.w = Ex[s] * ey;
        reinterpret_cast<float4*>(ob)[idx] = v;
    }
}

// ---------------------------------------------------------------- launch
extern "C" void kernel_launch(void* const* d_in, const int* in_sizes, int n_in,
                              void* d_out, int out_size, void* d_ws, size_t ws_size,
                              hipStream_t stream) {
    const float* hiddens = (const float*)d_in[0];
    const int* masks     = (const int*)d_in[1];   // jax bool -> int32 in harness
    const float* queries = (const float*)d_in[2];
    const float* qlocs   = (const float*)d_in[3];
    const float* qlogits = (const float*)d_in[4];
    const float* Wc = (const float*)d_in[5];
    const float* bc = (const float*)d_in[6];
    const float* Wq = (const float*)d_in[7];
    const float* bq = (const float*)d_in[8];
    const float* Wv = (const float*)d_in[9];
    const float* bv = (const float*)d_in[10];
    const float* Wo = (const float*)d_in[11];
    const float* bo = (const float*)d_in[12];
    const float* Wf = (const float*)d_in[13];
    const float* bf = (const float*)d_in[14];
    float* out = (float*)d_out;
    float* ws  = (float*)d_ws;     // needs 6.30 MB

    hipLaunchKernelGGL(k_front, dim3(224),  dim3(256), 0, stream, hiddens, Wv, ws);
    hipLaunchKernelGGL(k_qhg,   dim3(128),  dim3(512), 0, stream,
                       queries, Wq, bq, bv, qlocs, qlogits, Wc, bc, Wo, bo, Wf, bf, ws, out);
    hipLaunchKernelGGL(k_prep,  dim3(512),  dim3(384), 0, stream, ws, ws, masks);
    hipLaunchKernelGGL(k_write, dim3(2048), dim3(256), 0, stream, ws, out);
}